// Round 3
// baseline (74.618 us; speedup 1.0000x reference)
//
#include <hip/hip_runtime.h>

#define DD 8
#define MPT 4                       // outputs per thread
#define LOG2E_HALF 0.7213475204444817f  // 0.5 / ln(2)

// Single fused kernel. Each block recomputes the 216 pair-independent
// coefficients into LDS (864 B, ~64 threads, trivially cheap), then each
// thread produces MPT=4 outputs so every LDS coefficient broadcast is
// amortized over 4 FMAs.
//   cf[  0.. 63] : B[c][k] = 0.5*log2e*inv2[c][k]  (exp2 argument matrix)
//   cf[ 64..127] : G[j][c] = s0*sJ*M[c,j]
//   cf[128..191] : K[j][c] = s0*sJ*M[c,j]^2
//   cf[192..199] : l2[j]   = L[0,j]^2
//   cf[200..207] : r1[d]   = -4*s0*sd*tl[d]
//   cf[208..215] : r0[d]   =  2*s0*sd
__global__ __launch_bounds__(256) void rbf_fused(
        const float* __restrict__ x1, const float* __restrict__ x2,
        const float* __restrict__ L, const float* __restrict__ sigma,
        float* __restrict__ out, int N, int M) {
    __shared__ float cf[216];
    const int t = threadIdx.x;
    if (t < 64) {
        const int j = t >> 3, c = t & 7;
        float s0   = sigma[0];
        float Ljc  = L[j * DD + c];
        float i2jc = 1.0f / (Ljc * Ljc);
        cf[j * DD + c] = LOG2E_HALF * i2jc;
        float L0j = L[j];
        float l2j = L0j * L0j;
        float sJ  = sigma[j] / (l2j * l2j);
        float L0c = L[c];
        float Mcj = 1.0f / (L0c * L0c) + i2jc;       // inv2[0,c] + inv2[j,c]
        float G   = s0 * sJ * Mcj;
        cf[64  + j * DD + c] = G;
        cf[128 + j * DD + c] = G * Mcj;
        if (t < DD) {
            int d = t;
            float L0d = L[d];
            float l2  = L0d * L0d;
            cf[192 + d] = l2;
            float Ldd = L[d * DD + d];
            float tl  = 1.0f / l2 + 1.0f / (Ldd * Ldd);
            float sd  = sigma[d] / (l2 * l2);
            cf[200 + d] = -4.0f * s0 * sd * tl;
            cf[208 + d] =  2.0f * s0 * sd;
        }
    }
    __syncthreads();

    const int n  = blockIdx.y;
    const int m0 = blockIdx.x * (MPT * 256);

    // x1 row is block-uniform -> scalar loads
    const float* xr = x1 + (size_t)n * DD;
    float xv[DD];
#pragma unroll
    for (int k = 0; k < DD; ++k) xv[k] = xr[k];

    float dd[MPT][DD], e[MPT][DD], w[MPT][DD];
#pragma unroll
    for (int q = 0; q < MPT; ++q) {
        int m = m0 + t + q * 256;
        int mc = m < M ? m : M - 1;                  // clamp loads, guard stores
        const float4 ya = *reinterpret_cast<const float4*>(x2 + (size_t)mc * DD);
        const float4 yb = *reinterpret_cast<const float4*>(x2 + (size_t)mc * DD + 4);
        float yv[DD] = {ya.x, ya.y, ya.z, ya.w, yb.x, yb.y, yb.z, yb.w};
#pragma unroll
        for (int k = 0; k < DD; ++k) {
            float dif = xv[k] - yv[k];
            dd[q][k] = dif * dif;
        }
    }

    // e[q][c] = exp2(-sum_k dd*B),  w = dd*e
#pragma unroll
    for (int c = 0; c < DD; ++c) {
        float bc[DD];
#pragma unroll
        for (int k = 0; k < DD; ++k) bc[k] = cf[c * DD + k];
#pragma unroll
        for (int q = 0; q < MPT; ++q) {
            float A = 0.0f;
#pragma unroll
            for (int k = 0; k < DD; ++k) A = fmaf(dd[q][k], bc[k], A);
            float ec = exp2f(-A);
            e[q][c] = ec;
            w[q][c] = dd[q][c] * ec;
        }
    }

    float acc[MPT] = {0.0f, 0.0f, 0.0f, 0.0f};
#pragma unroll
    for (int j = 0; j < DD; ++j) {
        float gr[DD], kr[DD];
#pragma unroll
        for (int c = 0; c < DD; ++c) {
            gr[c] = cf[64  + j * DD + c];
            kr[c] = cf[128 + j * DD + c];
        }
        float l2 = cf[192 + j];
#pragma unroll
        for (int q = 0; q < MPT; ++q) {
            float ge = 0.0f, kw = 0.0f;
#pragma unroll
            for (int c = 0; c < DD; ++c) {
                ge = fmaf(gr[c], e[q][c], ge);
                kw = fmaf(kr[c], w[q][c], kw);
            }
            float fj = (l2 - dd[q][j]) * e[q][j];
            acc[q] = fmaf(fj, ge - kw, acc[q]);
        }
    }

    // diagonal correction: sum_d (r0 + r1*dd) * e^2
#pragma unroll
    for (int d = 0; d < DD; ++d) {
        float r1 = cf[200 + d], r0 = cf[208 + d];
#pragma unroll
        for (int q = 0; q < MPT; ++q) {
            float adj = fmaf(r1, dd[q][d], r0);
            acc[q] = fmaf(adj * e[q][d], e[q][d], acc[q]);
        }
    }

#pragma unroll
    for (int q = 0; q < MPT; ++q) {
        int m = m0 + t + q * 256;
        if (m < M) out[(size_t)n * M + m] = e[q][0] * acc[q];
    }
}

extern "C" void kernel_launch(void* const* d_in, const int* in_sizes, int n_in,
                              void* d_out, int out_size, void* d_ws, size_t ws_size,
                              hipStream_t stream) {
    const float* x1 = (const float*)d_in[0];
    const float* x2 = (const float*)d_in[1];
    const float* L  = (const float*)d_in[2];
    const float* sg = (const float*)d_in[3];
    float* out = (float*)d_out;

    int N = in_sizes[0] / DD;
    int M = in_sizes[1] / DD;

    dim3 grid((M + MPT * 256 - 1) / (MPT * 256), N);
    rbf_fused<<<grid, 256, 0, stream>>>(x1, x2, L, sg, out, N, M);
}